// Round 9
// baseline (919.165 us; speedup 1.0000x reference)
//
#include <hip/hip_runtime.h>
#include <hip/hip_bf16.h>

typedef __attribute__((ext_vector_type(8))) short bf16x8;
typedef __attribute__((ext_vector_type(4))) short s16x4;
typedef __attribute__((ext_vector_type(4))) float f32x4;

__device__ __forceinline__ short f2bf(float f) {
  union { __hip_bfloat16 h; short s; } u;
  u.h = __float2bfloat16(f);
  return u.s;
}

__device__ __forceinline__ void gld_lds16(const short* g, short* l) {
  __builtin_amdgcn_global_load_lds((const __attribute__((address_space(1))) unsigned*)g,
                                   (__attribute__((address_space(3))) unsigned*)l,
                                   16, 0, 0);
}

// fp32 -> bf16 bulk convert (8 elems/thread, grid-stride)
__global__ void cvt_kernel(const float* __restrict__ in, short* __restrict__ out, long n8) {
  long i = (long)blockIdx.x * blockDim.x + threadIdx.x;
  const long stride = (long)gridDim.x * blockDim.x;
  for (; i < n8; i += stride) {
    const float* p = in + i * 8;
    float4 a = *(const float4*)p, b = *(const float4*)(p + 4);
    bf16x8 o;
    o[0] = f2bf(a.x); o[1] = f2bf(a.y); o[2] = f2bf(a.z); o[3] = f2bf(a.w);
    o[4] = f2bf(b.x); o[5] = f2bf(b.y); o[6] = f2bf(b.z); o[7] = f2bf(b.w);
    *(bf16x8*)(out + i * 8) = o;
  }
}

// W[K][N] fp32 -> bf16 fragment slots: slot s = (kc*(N/16)+f)*64 + lane, lane=(kg,l16)
// content: W[k(kc*32+kg*8+e)][f*16+l16].  PERM: k-col permutation matching H storage:
// k = (kh & ~63) | ((kh&3)<<4) | ((kh>>2)&15)
template <bool PERM>
__global__ void prep_kernel(const float* __restrict__ W, short* __restrict__ out, int K, int N) {
  int s = blockIdx.x * 256 + threadIdx.x;
  int NF = N >> 4;
  int total = (K >> 5) * NF * 64;
  if (s >= total) return;
  int l = s & 63, kcf = s >> 6;
  int kc = kcf / NF, f = kcf - kc * NF;
  int kg = l >> 4, l16 = l & 15;
  bf16x8 o;
#pragma unroll
  for (int e = 0; e < 8; ++e) {
    int kh = kc * 32 + kg * 8 + e;
    int k = PERM ? ((kh & ~63) | ((kh & 3) << 4) | ((kh >> 2) & 15)) : kh;
    o[e] = f2bf(W[(size_t)k * N + f * 16 + l16]);
  }
  *(bf16x8*)(out + (size_t)s * 8) = o;
}

// ---------------- CSR aggregation ----------------
__global__ void count_kernel(const int* __restrict__ dst, int* __restrict__ cnt, int E) {
  int i = blockIdx.x * 256 + threadIdx.x;
  if (i < E) atomicAdd(&cnt[dst[i]], 1);
}

__global__ __launch_bounds__(1024) void scan_kernel(const int* __restrict__ cnt,
                                                    int* __restrict__ off,
                                                    int* __restrict__ cursor, int N) {
  __shared__ int wsum[16];
  const int t = threadIdx.x;
  const int w = t >> 6, l = t & 63;
  int running = 0;
  for (int base = 0; base < N; base += 1024) {
    int i = base + t;
    int v = (i < N) ? cnt[i] : 0;
    int x = v;
#pragma unroll
    for (int d = 1; d < 64; d <<= 1) { int y = __shfl_up(x, d); if (l >= d) x += y; }
    if (l == 63) wsum[w] = x;
    __syncthreads();
    if (w == 0) {
      int s = (l < 16) ? wsum[l] : 0;
#pragma unroll
      for (int d = 1; d < 16; d <<= 1) { int y = __shfl_up(s, d); if (l >= d) s += y; }
      if (l < 16) wsum[l] = s;
    }
    __syncthreads();
    int total = wsum[15];
    int wo = (w > 0) ? wsum[w - 1] : 0;
    int excl = running + wo + x - v;
    if (i < N) { off[i] = excl; cursor[i] = excl; }
    running += total;
    __syncthreads();
  }
  if (t == 0) off[N] = running;
}

__global__ void scatter_kernel(const int* __restrict__ dst, int* __restrict__ cursor,
                               int* __restrict__ eidx, int E) {
  int e = blockIdx.x * 256 + threadIdx.x;
  if (e < E) {
    int p = atomicAdd(&cursor[dst[e]], 1);
    eidx[p] = e;
  }
}

// per-node gather-mean of new edge embeddings -> bf16
__global__ void agg_kernel(const float* __restrict__ edge_out, const int* __restrict__ eidx,
                           const int* __restrict__ off, short* __restrict__ aggb, int N) {
  int n = blockIdx.x * 4 + (threadIdx.x >> 6);
  if (n >= N) return;
  int l = threadIdx.x & 63;
  int beg = off[n], end = off[n + 1];
  float ax = 0.f, ay = 0.f;
  int i = beg;
  for (; i + 4 <= end; i += 4) {
    int e0 = eidx[i], e1 = eidx[i + 1], e2 = eidx[i + 2], e3 = eidx[i + 3];
    float2 v0 = *(const float2*)(edge_out + (size_t)e0 * 128 + l * 2);
    float2 v1 = *(const float2*)(edge_out + (size_t)e1 * 128 + l * 2);
    float2 v2 = *(const float2*)(edge_out + (size_t)e2 * 128 + l * 2);
    float2 v3 = *(const float2*)(edge_out + (size_t)e3 * 128 + l * 2);
    ax += v0.x + v1.x + v2.x + v3.x;
    ay += v0.y + v1.y + v2.y + v3.y;
  }
  for (; i < end; ++i) {
    int e = eidx[i];
    float2 v = *(const float2*)(edge_out + (size_t)e * 128 + l * 2);
    ax += v.x; ay += v.y;
  }
  float inv = 1.0f / fmaxf((float)(end - beg), 1.0f);
  unsigned pk = ((unsigned)(unsigned short)f2bf(ay * inv) << 16) |
                (unsigned)(unsigned short)f2bf(ax * inv);
  *(unsigned*)&aggb[(size_t)n * 128 + l * 2] = pk;
}

// ---------------- fused 3-layer MLP + LN, BM=128, 512 thr ----------------
// Wave grid L1/L2: 2(row wr)x4(col wc), tile 64r x 64c (4x4 frags).
// L3: same wr; wc owns 32 of 128 cols (4x2 frags); LN via cross-wave partials.
// B-fragments: loaded global->VGPR per wave (prepped frag-linear, coalesced, depth-2
// rotation) -- NO LDS, NO barriers for weights. Barriers only for L1 A-staging dbuf
// and H handoffs (~11/block vs 26 before).
// H: addr(row, ch) = row*256 + (ch ^ ((row&7)<<3)); position ch holds col
// c = ((ch&3)<<4)|((ch>>2)&15) per 64-block (matches PERM'd W2/W3 K-order).
template <bool IS_EDGE>
__launch_bounds__(512, 2)
__global__ void mlp_kernel(const float* __restrict__ node_emb_f, const float* __restrict__ edge_emb_f,
                           const short* __restrict__ node_bf, const short* __restrict__ agg_bf,
                           const int* __restrict__ src, const int* __restrict__ dst,
                           const short* __restrict__ wAll,
                           const float* __restrict__ b1, const float* __restrict__ b2,
                           const float* __restrict__ b3,
                           const float* __restrict__ gam, const float* __restrict__ bet,
                           float* __restrict__ out_base, int M) {
  extern __shared__ short smem[];
  short* As = smem;                          // 2 x 8192 shorts (32 KB): L1 A dbuf (2 chunks/group)
  short* Hs = smem + 16384;                  // 32768 shorts (64 KB): 128 x 256
  float2* pbuf = (float2*)(smem + 49152);    // 4 KB LN partials

  const int tid = threadIdx.x;
  const int m0 = blockIdx.x * 128;
  const int w = tid >> 6, lane = tid & 63, l16 = lane & 15, kg = lane >> 4;
  const int wr = w >> 2, wc = w & 3;

  constexpr int NC1 = IS_EDGE ? 12 : 8;
  constexpr int NG = NC1 / 2;
  const short* w2p = wAll + (size_t)NC1 * 8192;
  const short* w3p = w2p + 8 * 8192;

  // staging identity: each thread owns row srow for slots {tid, tid+512}
  const int srow = ((tid >> 6) & 7) * 16 + (tid & 15);
  const int src_rc = min(m0 + srow, M - 1);
  const int kgo = ((tid >> 4) & 3) * 8;
  int gsr = 0, gdr = 0;
  if (IS_EDGE) { gsr = src[src_rc]; gdr = dst[src_rc]; }

  float b1v[4], b2v[4];
#pragma unroll
  for (int ct = 0; ct < 4; ++ct) {
    int col = wc * 64 + ct * 16 + l16;
    b1v[ct] = b1[col];
    b2v[ct] = b2[col];
  }

  f32x4 acc[16];
#pragma unroll
  for (int i = 0; i < 16; ++i) { f32x4 z = {0.f, 0.f, 0.f, 0.f}; acc[i] = z; }

  auto stageG = [&](int g, int buf) {
#pragma unroll
    for (int j = 0; j < 2; ++j) {
      int cb = g * 64 + j * 32 + kgo;
      short* ldst = As + (size_t)buf * 8192 + (size_t)(j * 512 + tid) * 8;
      if (IS_EDGE) {
        if (cb < 256) {
          const short* q = node_bf + (size_t)(cb < 128 ? gsr : gdr) * 128 + (cb & 127);
          gld_lds16(q, ldst);
        } else {
          const float* q = edge_emb_f + (size_t)src_rc * 128 + (cb - 256);
          float4 a = *(const float4*)q, bb = *(const float4*)(q + 4);
          bf16x8 o;
          o[0] = f2bf(a.x);  o[1] = f2bf(a.y);  o[2] = f2bf(a.z);  o[3] = f2bf(a.w);
          o[4] = f2bf(bb.x); o[5] = f2bf(bb.y); o[6] = f2bf(bb.z); o[7] = f2bf(bb.w);
          *(bf16x8*)ldst = o;
        }
      } else {
        const short* q = (cb < 128) ? node_bf + (size_t)src_rc * 128 + cb
                                    : agg_bf + (size_t)src_rc * 128 + (cb - 128);
        gld_lds16(q, ldst);
      }
    }
  };

  auto loadB1 = [&](int kc, bf16x8* bb) {
#pragma unroll
    for (int ct = 0; ct < 4; ++ct)
      bb[ct] = *(const bf16x8*)(wAll + ((size_t)((kc * 16 + wc * 4 + ct) * 64 + lane)) * 8);
  };
  auto loadB2 = [&](int kc, bf16x8* bb) {
#pragma unroll
    for (int ct = 0; ct < 4; ++ct)
      bb[ct] = *(const bf16x8*)(w2p + ((size_t)((kc * 16 + wc * 4 + ct) * 64 + lane)) * 8);
  };
  auto loadB3 = [&](int kc, bf16x8* bb) {
#pragma unroll
    for (int ct = 0; ct < 2; ++ct)
      bb[ct] = *(const bf16x8*)(w3p + ((size_t)((kc * 8 + wc * 2 + ct) * 64 + lane)) * 8);
  };

  auto compA = [&](int kcl, int buf, bf16x8* bb) {
    bf16x8 a[4];
#pragma unroll
    for (int rt = 0; rt < 4; ++rt)
      a[rt] = *(const bf16x8*)&As[(size_t)buf * 8192 + (size_t)(kcl * 512 + (wr * 4 + rt) * 64 + lane) * 8];
#pragma unroll
    for (int rt = 0; rt < 4; ++rt)
#pragma unroll
      for (int ct = 0; ct < 4; ++ct)
        acc[rt * 4 + ct] = __builtin_amdgcn_mfma_f32_16x16x32_bf16(a[rt], bb[ct], acc[rt * 4 + ct], 0, 0, 0);
  };

  auto compH = [&](int kc, bf16x8* bb) {
    bf16x8 a[4];
#pragma unroll
    for (int rt = 0; rt < 4; ++rt) {
      int row = wr * 64 + rt * 16 + l16;
      int ch = (kc * 32 + kg * 8) ^ ((row & 7) << 3);
      a[rt] = *(const bf16x8*)&Hs[(size_t)row * 256 + ch];
    }
#pragma unroll
    for (int rt = 0; rt < 4; ++rt)
#pragma unroll
      for (int ct = 0; ct < 4; ++ct)
        acc[rt * 4 + ct] = __builtin_amdgcn_mfma_f32_16x16x32_bf16(a[rt], bb[ct], acc[rt * 4 + ct], 0, 0, 0);
  };

  auto writeH = [&](const float* bv) {
#pragma unroll
    for (int rt = 0; rt < 4; ++rt)
#pragma unroll
      for (int q = 0; q < 4; ++q) {
        int row = wr * 64 + rt * 16 + kg * 4 + q;
        s16x4 v;
#pragma unroll
        for (int ct = 0; ct < 4; ++ct)
          v[ct] = f2bf(fmaxf(acc[rt * 4 + ct][q] + bv[ct], 0.f));
        int ch = (wc * 64 + l16 * 4) ^ ((row & 7) << 3);
        *(s16x4*)&Hs[(size_t)row * 256 + ch] = v;
      }
#pragma unroll
    for (int i = 0; i < 16; ++i) { f32x4 z = {0.f, 0.f, 0.f, 0.f}; acc[i] = z; }
  };

  // ---- layer 1: NG groups of 2 chunks; A dbuf; B global->reg ----
  stageG(0, 0);
  __syncthreads();
  bf16x8 bc[4], bn[4];
#pragma unroll
  for (int g = 0; g < NG; ++g) {
    if (g + 1 < NG) stageG(g + 1, (g + 1) & 1);
    loadB1(2 * g, bc);
    loadB1(2 * g + 1, bn);
    compA(0, g & 1, bc);
    compA(1, g & 1, bn);
    __syncthreads();
  }
  writeH(b1v);
  __syncthreads();

  // ---- layer 2: 8 chunks, ZERO barriers (A from H, B depth-2 reg rotation) ----
  loadB2(0, bc);
  loadB2(1, bn);
#pragma unroll
  for (int kc = 0; kc < 8; ++kc) {
    bf16x8 bnew[4];
    if (kc + 2 < 8) loadB2(kc + 2, bnew);
    compH(kc, bc);
#pragma unroll
    for (int ct = 0; ct < 4; ++ct) { bc[ct] = bn[ct]; bn[ct] = bnew[ct]; }
  }
  __syncthreads();  // all L2 H-reads done
  writeH(b2v);
  __syncthreads();

  // ---- layer 3: 8 chunks, zero barriers; wave = 64r x 32c ----
  bf16x8 c0[2], c1[2];
  loadB3(0, c0);
  loadB3(1, c1);
#pragma unroll
  for (int kc = 0; kc < 8; ++kc) {
    bf16x8 cn[2];
    if (kc + 2 < 8) loadB3(kc + 2, cn);
    bf16x8 a[4];
#pragma unroll
    for (int rt = 0; rt < 4; ++rt) {
      int row = wr * 64 + rt * 16 + l16;
      int ch = (kc * 32 + kg * 8) ^ ((row & 7) << 3);
      a[rt] = *(const bf16x8*)&Hs[(size_t)row * 256 + ch];
    }
#pragma unroll
    for (int rt = 0; rt < 4; ++rt)
#pragma unroll
      for (int ct = 0; ct < 2; ++ct)
        acc[rt * 2 + ct] = __builtin_amdgcn_mfma_f32_16x16x32_bf16(a[rt], c0[ct], acc[rt * 2 + ct], 0, 0, 0);
#pragma unroll
    for (int ct = 0; ct < 2; ++ct) { c0[ct] = c1[ct]; c1[ct] = cn[ct]; }
  }

  // ---- epilogue: bias + cross-wave LayerNorm + residual ----
  float b3v[2], gv[2], bev[2];
#pragma unroll
  for (int ct = 0; ct < 2; ++ct) {
    int col = wc * 32 + ct * 16 + l16;
    b3v[ct] = b3[col]; gv[ct] = gam[col]; bev[ct] = bet[col];
  }
#pragma unroll
  for (int rt = 0; rt < 4; ++rt)
#pragma unroll
    for (int q = 0; q < 4; ++q) {
      int row = wr * 64 + rt * 16 + kg * 4 + q;
      float x0 = acc[rt * 2 + 0][q] + b3v[0];
      float x1 = acc[rt * 2 + 1][q] + b3v[1];
      acc[rt * 2 + 0][q] = x0;
      acc[rt * 2 + 1][q] = x1;
      float s1 = x0 + x1, s2 = x0 * x0 + x1 * x1;
#pragma unroll
      for (int m = 1; m <= 8; m <<= 1) { s1 += __shfl_xor(s1, m); s2 += __shfl_xor(s2, m); }
      if (l16 == 0) pbuf[row * 4 + wc] = make_float2(s1, s2);
    }
  __syncthreads();
#pragma unroll
  for (int rt = 0; rt < 4; ++rt)
#pragma unroll
    for (int q = 0; q < 4; ++q) {
      int row = wr * 64 + rt * 16 + kg * 4 + q;
      float2 p0 = pbuf[row * 4 + 0];
      float2 p1 = pbuf[row * 4 + 1];
      float2 p2 = pbuf[row * 4 + 2];
      float2 p3 = pbuf[row * 4 + 3];
      float S1 = p0.x + p1.x + p2.x + p3.x;
      float S2 = p0.y + p1.y + p2.y + p3.y;
      float mu = S1 * (1.f / 128.f);
      float var = S2 * (1.f / 128.f) - mu * mu;
      float rs = rsqrtf(var + 1e-5f);
      int rg = m0 + row;
      if (rg < M) {
        const float* resid = (IS_EDGE ? edge_emb_f : node_emb_f) + (size_t)rg * 128;
        float* op = out_base + (size_t)rg * 128;
#pragma unroll
        for (int ct = 0; ct < 2; ++ct) {
          int col = wc * 32 + ct * 16 + l16;
          op[col] = (acc[rt * 2 + ct][q] - mu) * rs * gv[ct] + bev[ct] + resid[col];
        }
      }
    }
}

extern "C" void kernel_launch(void* const* d_in, const int* in_sizes, int n_in,
                              void* d_out, int out_size, void* d_ws, size_t ws_size,
                              hipStream_t stream) {
  const float* node_emb = (const float*)d_in[0];
  const float* edge_emb = (const float*)d_in[1];
  const int*   src      = (const int*)d_in[2];
  const int*   dst      = (const int*)d_in[3];
  const float* eW1 = (const float*)d_in[5];
  const float* eb1 = (const float*)d_in[6];
  const float* eW2 = (const float*)d_in[7];
  const float* eb2 = (const float*)d_in[8];
  const float* eW3 = (const float*)d_in[9];
  const float* eb3 = (const float*)d_in[10];
  const float* eg  = (const float*)d_in[11];
  const float* ebt = (const float*)d_in[12];
  const float* nW1 = (const float*)d_in[13];
  const float* nb1 = (const float*)d_in[14];
  const float* nW2 = (const float*)d_in[15];
  const float* nb2 = (const float*)d_in[16];
  const float* nW3 = (const float*)d_in[17];
  const float* nb3 = (const float*)d_in[18];
  const float* ng  = (const float*)d_in[19];
  const float* nbt = (const float*)d_in[20];

  const int Nn = in_sizes[0] / 128;
  const int Ee = in_sizes[2];

  char* ws = (char*)d_ws;
  short* aggb   = (short*)ws;  ws += (size_t)Nn * 128 * 2;
  short* nodebf = (short*)ws;  ws += (size_t)Nn * 128 * 2;
  int* cnt_i  = (int*)ws;      ws += (size_t)Nn * 4;
  int* cursor = (int*)ws;      ws += (size_t)Nn * 4;
  int* offv   = (int*)ws;      ws += (size_t)(Nn + 1) * 4;
  int* eidx   = (int*)ws;      ws += (size_t)Ee * 4;
  ws = (char*)(((uintptr_t)ws + 15) & ~(uintptr_t)15);
  short* eAll = (short*)ws;          // W1 12x8192 | W2 8x8192 | W3 8x4096 = 196608 shorts
  short* nAll = eAll + 196608;       // W1 8x8192 | W2 8x8192 | W3 8x4096 = 163840 shorts

  float* out_node = (float*)d_out;
  float* out_edge = out_node + (size_t)Nn * 128;

  hipMemsetAsync(cnt_i, 0, (size_t)Nn * 4, stream);

  cvt_kernel<<<2048, 256, 0, stream>>>(node_emb, nodebf, (long)Nn * 16);

  prep_kernel<false><<<48, 256, 0, stream>>>(eW1, eAll, 384, 256);
  prep_kernel<true><<<32, 256, 0, stream>>>(eW2, eAll + 98304, 256, 256);
  prep_kernel<true><<<16, 256, 0, stream>>>(eW3, eAll + 163840, 256, 128);
  prep_kernel<false><<<32, 256, 0, stream>>>(nW1, nAll, 256, 256);
  prep_kernel<true><<<32, 256, 0, stream>>>(nW2, nAll + 65536, 256, 256);
  prep_kernel<true><<<16, 256, 0, stream>>>(nW3, nAll + 131072, 256, 128);

  count_kernel<<<(Ee + 255) / 256, 256, 0, stream>>>(dst, cnt_i, Ee);
  scan_kernel<<<1, 1024, 0, stream>>>(cnt_i, offv, cursor, Nn);
  scatter_kernel<<<(Ee + 255) / 256, 256, 0, stream>>>(dst, cursor, eidx, Ee);

  mlp_kernel<true><<<(Ee + 127) / 128, 512, 102400, stream>>>(
      node_emb, edge_emb, nodebf, aggb, src, dst, eAll,
      eb1, eb2, eb3, eg, ebt, out_edge, Ee);

  agg_kernel<<<(Nn + 3) / 4, 256, 0, stream>>>(out_edge, eidx, offv, aggb, Nn);

  mlp_kernel<false><<<(Nn + 127) / 128, 512, 102400, stream>>>(
      node_emb, edge_emb, nodebf, aggb, src, dst, nAll,
      nb1, nb2, nb3, ng, nbt, out_node, Nn);
}

// Round 10
// 844.471 us; speedup vs baseline: 1.0885x; 1.0885x over previous
//
#include <hip/hip_runtime.h>
#include <hip/hip_bf16.h>

typedef __attribute__((ext_vector_type(8))) short bf16x8;
typedef __attribute__((ext_vector_type(4))) short s16x4;
typedef __attribute__((ext_vector_type(4))) float f32x4;

__device__ __forceinline__ short f2bf(float f) {
  union { __hip_bfloat16 h; short s; } u;
  u.h = __float2bfloat16(f);
  return u.s;
}

__device__ __forceinline__ void gld_lds16(const short* g, short* l) {
  __builtin_amdgcn_global_load_lds((const __attribute__((address_space(1))) unsigned*)g,
                                   (__attribute__((address_space(3))) unsigned*)l,
                                   16, 0, 0);
}

#define BARX0() asm volatile("s_waitcnt vmcnt(0) lgkmcnt(0)\ns_barrier" ::: "memory")
#define BARLG() asm volatile("s_waitcnt lgkmcnt(0)\ns_barrier" ::: "memory")

// fp32 -> bf16 bulk convert
__global__ void cvt_kernel(const float* __restrict__ in, short* __restrict__ out, long n8) {
  long i = (long)blockIdx.x * blockDim.x + threadIdx.x;
  const long stride = (long)gridDim.x * blockDim.x;
  for (; i < n8; i += stride) {
    const float* p = in + i * 8;
    float4 a = *(const float4*)p, b = *(const float4*)(p + 4);
    bf16x8 o;
    o[0] = f2bf(a.x); o[1] = f2bf(a.y); o[2] = f2bf(a.z); o[3] = f2bf(a.w);
    o[4] = f2bf(b.x); o[5] = f2bf(b.y); o[6] = f2bf(b.z); o[7] = f2bf(b.w);
    *(bf16x8*)(out + i * 8) = o;
  }
}

// W[K][N] fp32 -> bf16 fragment slots: slot s = (kc*(N/16)+f)*64 + lane, lane=(kg,l16)
// content: W[k(kc*32+kg*8+e)][f*16+l16].  PERM: k-col permutation matching H storage:
// k = (kh & ~63) | ((kh&3)<<4) | ((kh>>2)&15)
template <bool PERM>
__global__ void prep_kernel(const float* __restrict__ W, short* __restrict__ out, int K, int N) {
  int s = blockIdx.x * 256 + threadIdx.x;
  int NF = N >> 4;
  int total = (K >> 5) * NF * 64;
  if (s >= total) return;
  int l = s & 63, kcf = s >> 6;
  int kc = kcf / NF, f = kcf - kc * NF;
  int kg = l >> 4, l16 = l & 15;
  bf16x8 o;
#pragma unroll
  for (int e = 0; e < 8; ++e) {
    int kh = kc * 32 + kg * 8 + e;
    int k = PERM ? ((kh & ~63) | ((kh & 3) << 4) | ((kh >> 2) & 15)) : kh;
    o[e] = f2bf(W[(size_t)k * N + f * 16 + l16]);
  }
  *(bf16x8*)(out + (size_t)s * 8) = o;
}

// ---------------- CSR aggregation ----------------
__global__ void count_kernel(const int* __restrict__ dst, int* __restrict__ cnt, int E) {
  int i = blockIdx.x * 256 + threadIdx.x;
  if (i < E) atomicAdd(&cnt[dst[i]], 1);
}

__global__ __launch_bounds__(1024) void scan_kernel(const int* __restrict__ cnt,
                                                    int* __restrict__ off,
                                                    int* __restrict__ cursor, int N) {
  __shared__ int wsum[16];
  const int t = threadIdx.x;
  const int w = t >> 6, l = t & 63;
  int running = 0;
  for (int base = 0; base < N; base += 1024) {
    int i = base + t;
    int v = (i < N) ? cnt[i] : 0;
    int x = v;
#pragma unroll
    for (int d = 1; d < 64; d <<= 1) { int y = __shfl_up(x, d); if (l >= d) x += y; }
    if (l == 63) wsum[w] = x;
    __syncthreads();
    if (w == 0) {
      int s = (l < 16) ? wsum[l] : 0;
#pragma unroll
      for (int d = 1; d < 16; d <<= 1) { int y = __shfl_up(s, d); if (l >= d) s += y; }
      if (l < 16) wsum[l] = s;
    }
    __syncthreads();
    int total = wsum[15];
    int wo = (w > 0) ? wsum[w - 1] : 0;
    int excl = running + wo + x - v;
    if (i < N) { off[i] = excl; cursor[i] = excl; }
    running += total;
    __syncthreads();
  }
  if (t == 0) off[N] = running;
}

__global__ void scatter_kernel(const int* __restrict__ dst, int* __restrict__ cursor,
                               int* __restrict__ eidx, int E) {
  int e = blockIdx.x * 256 + threadIdx.x;
  if (e < E) {
    int p = atomicAdd(&cursor[dst[e]], 1);
    eidx[p] = e;
  }
}

// per-node gather-mean of new edge embeddings -> bf16
__global__ void agg_kernel(const float* __restrict__ edge_out, const int* __restrict__ eidx,
                           const int* __restrict__ off, short* __restrict__ aggb, int N) {
  int n = blockIdx.x * 4 + (threadIdx.x >> 6);
  if (n >= N) return;
  int l = threadIdx.x & 63;
  int beg = off[n], end = off[n + 1];
  float ax = 0.f, ay = 0.f;
  int i = beg;
  for (; i + 4 <= end; i += 4) {
    int e0 = eidx[i], e1 = eidx[i + 1], e2 = eidx[i + 2], e3 = eidx[i + 3];
    float2 v0 = *(const float2*)(edge_out + (size_t)e0 * 128 + l * 2);
    float2 v1 = *(const float2*)(edge_out + (size_t)e1 * 128 + l * 2);
    float2 v2 = *(const float2*)(edge_out + (size_t)e2 * 128 + l * 2);
    float2 v3 = *(const float2*)(edge_out + (size_t)e3 * 128 + l * 2);
    ax += v0.x + v1.x + v2.x + v3.x;
    ay += v0.y + v1.y + v2.y + v3.y;
  }
  for (; i < end; ++i) {
    int e = eidx[i];
    float2 v = *(const float2*)(edge_out + (size_t)e * 128 + l * 2);
    ax += v.x; ay += v.y;
  }
  float inv = 1.0f / fmaxf((float)(end - beg), 1.0f);
  unsigned pk = ((unsigned)(unsigned short)f2bf(ay * inv) << 16) |
                (unsigned)(unsigned short)f2bf(ax * inv);
  *(unsigned*)&aggb[(size_t)n * 128 + l * 2] = pk;
}

// ---------------- fused 3-layer MLP + LN, BM=128, 512 thr, K=64 intervals ----------------
// Wave grid L1/L2: 2(row wr)x4(col wc), tile 64r x 64c (4x4 frags).
// L3: wave = 64r x 32c (4x2 frags); LN via cross-wave partials.
// Weight stream wAll = uniform 16384-short (32 KB) units (2 chunks of N=256 or 4 of N=128),
// double-buffered, one counted barrier per unit: 12 intervals (edge) / 10 (node).
// H: addr(row, ch) = row*256 + (ch ^ ((row&7)<<3)); position ch holds col
// c = ((ch&3)<<4)|((ch>>2)&15) per 64-block (matches PERM'd W2/W3 K-order).
// L1 A-chunks (dbuf 2x16KB) overlay Hs (free until H1 is written).
template <bool IS_EDGE>
__launch_bounds__(512)
__global__ void mlp_kernel(const float* __restrict__ node_emb_f, const float* __restrict__ edge_emb_f,
                           const short* __restrict__ node_bf, const short* __restrict__ agg_bf,
                           const int* __restrict__ src, const int* __restrict__ dst,
                           const short* __restrict__ wAll,
                           const float* __restrict__ b1, const float* __restrict__ b2,
                           const float* __restrict__ b3,
                           const float* __restrict__ gam, const float* __restrict__ bet,
                           float* __restrict__ out_base, int M) {
  extern __shared__ short smem[];
  short* Bs = smem;                          // 2 x 16384 shorts (64 KB) weight unit dbuf
  short* Hs = smem + 32768;                  // 32768 shorts (64 KB); As dbuf overlays [0,16384)
  float2* pbuf = (float2*)(smem + 65536);    // 4 KB LN partials

  const int tid = threadIdx.x;
  const int m0 = blockIdx.x * 128;
  const int w = tid >> 6, lane = tid & 63, l16 = lane & 15, kg = lane >> 4;
  const int wr = w >> 2, wc = w & 3;

  constexpr int NL1 = IS_EDGE ? 6 : 4;   // K=64 units in layer 1
  constexpr int NU = NL1 + 4 + 2;        // + 4 L2 units + 2 L3 units

  // staging identity: thread stages row grow, 8-col group gcq (per 32-col chunk)
  const int grow = ((tid >> 6) & 7) * 16 + (tid & 15);
  const int gcq = ((tid >> 4) & 3) * 8;
  const int grc = min(m0 + grow, M - 1);
  int gsr = 0, gdr = 0;
  if (IS_EDGE) { gsr = src[grc]; gdr = dst[grc]; }

  float b1v[4], b2v[4];
#pragma unroll
  for (int ct = 0; ct < 4; ++ct) {
    int col = wc * 64 + ct * 16 + l16;
    b1v[ct] = b1[col];
    b2v[ct] = b2[col];
  }

  f32x4 acc[16];
#pragma unroll
  for (int i = 0; i < 16; ++i) { f32x4 z = {0.f, 0.f, 0.f, 0.f}; acc[i] = z; }

  auto stageW = [&](int v) {
    const short* g = wAll + (size_t)v * 16384;
    short* l = Bs + (size_t)(v & 1) * 16384;
#pragma unroll
    for (int s0 = 0; s0 < 4; ++s0)
      gld_lds16(g + (size_t)(s0 * 512 + tid) * 8, l + (size_t)(s0 * 512 + tid) * 8);
  };

  // stage A unit g (cols g*64..+63) into As[buf] (overlay on Hs)
  auto stageA = [&](int g, int buf) {
    short* Ab = Hs + (size_t)buf * 8192;
#pragma unroll
    for (int kcL = 0; kcL < 2; ++kcL) {
      int col = g * 64 + kcL * 32 + gcq;
      short* ldst = Ab + (size_t)(kcL * 512 + tid) * 8;
      if (IS_EDGE) {
        if (col < 256) {
          const short* q = node_bf + (size_t)(col < 128 ? gsr : gdr) * 128 + (col & 127);
          gld_lds16(q, ldst);
        } else {
          const float* q = edge_emb_f + (size_t)grc * 128 + (col - 256);
          float4 a = *(const float4*)q, bb = *(const float4*)(q + 4);
          bf16x8 o;
          o[0] = f2bf(a.x);  o[1] = f2bf(a.y);  o[2] = f2bf(a.z);  o[3] = f2bf(a.w);
          o[4] = f2bf(bb.x); o[5] = f2bf(bb.y); o[6] = f2bf(bb.z); o[7] = f2bf(bb.w);
          *(bf16x8*)ldst = o;
        }
      } else {
        const short* q = (col < 128) ? node_bf + (size_t)grc * 128 + col
                                     : agg_bf + (size_t)grc * 128 + (col - 128);
        gld_lds16(q, ldst);
      }
    }
  };

  auto mfma16 = [&](bf16x8* a, bf16x8* b) {
#pragma unroll
    for (int rt = 0; rt < 4; ++rt)
#pragma unroll
      for (int ct = 0; ct < 4; ++ct)
        acc[rt * 4 + ct] = __builtin_amdgcn_mfma_f32_16x16x32_bf16(a[rt], b[ct], acc[rt * 4 + ct], 0, 0, 0);
  };

  // L1 unit u: 2 chunks from As[u&1] x Bs[u&1]
  auto compA2 = [&](int u) {
    const short* Ab = Hs + (size_t)(u & 1) * 8192;
    const short* Bp = Bs + (size_t)(u & 1) * 16384;
#pragma unroll
    for (int kcL = 0; kcL < 2; ++kcL) {
      bf16x8 a[4], b[4];
#pragma unroll
      for (int rt = 0; rt < 4; ++rt)
        a[rt] = *(const bf16x8*)&Ab[(size_t)(kcL * 512 + (wr * 4 + rt) * 64 + kg * 16 + l16) * 8];
#pragma unroll
      for (int ct = 0; ct < 4; ++ct)
        b[ct] = *(const bf16x8*)&Bp[(size_t)(kcL * 1024 + (wc * 4 + ct) * 64 + lane) * 8];
      mfma16(a, b);
    }
  };

  // L2 unit u: 2 chunks, A from swizzled H
  auto compH2 = [&](int u) {
    const short* Bp = Bs + (size_t)(u & 1) * 16384;
#pragma unroll
    for (int kcL = 0; kcL < 2; ++kcL) {
      int kc = 2 * (u - NL1) + kcL;
      bf16x8 a[4], b[4];
#pragma unroll
      for (int rt = 0; rt < 4; ++rt) {
        int row = wr * 64 + rt * 16 + l16;
        int ch = (kc * 32 + kg * 8) ^ ((row & 7) << 3);
        a[rt] = *(const bf16x8*)&Hs[(size_t)row * 256 + ch];
      }
#pragma unroll
      for (int ct = 0; ct < 4; ++ct)
        b[ct] = *(const bf16x8*)&Bp[(size_t)(kcL * 1024 + (wc * 4 + ct) * 64 + lane) * 8];
      mfma16(a, b);
    }
  };

  auto writeH = [&](const float* bv) {
#pragma unroll
    for (int rt = 0; rt < 4; ++rt)
#pragma unroll
      for (int q = 0; q < 4; ++q) {
        int row = wr * 64 + rt * 16 + kg * 4 + q;
        s16x4 v;
#pragma unroll
        for (int ct = 0; ct < 4; ++ct)
          v[ct] = f2bf(fmaxf(acc[rt * 4 + ct][q] + bv[ct], 0.f));
        int ch = (wc * 64 + l16 * 4) ^ ((row & 7) << 3);
        *(s16x4*)&Hs[(size_t)row * 256 + ch] = v;
      }
#pragma unroll
    for (int i = 0; i < 16; ++i) { f32x4 z = {0.f, 0.f, 0.f, 0.f}; acc[i] = z; }
  };

  // L3 unit u: 4 chunks of W3 (N=128); wave = 64r x 32c; acc[0..7]
  auto compL3x4 = [&](int u) {
    const short* Bp = Bs + (size_t)(u & 1) * 16384;
#pragma unroll
    for (int j = 0; j < 4; ++j) {
      int kc = (u - (NL1 + 4)) * 4 + j;
      bf16x8 a[4], b[2];
#pragma unroll
      for (int rt = 0; rt < 4; ++rt) {
        int row = wr * 64 + rt * 16 + l16;
        int ch = (kc * 32 + kg * 8) ^ ((row & 7) << 3);
        a[rt] = *(const bf16x8*)&Hs[(size_t)row * 256 + ch];
      }
#pragma unroll
      for (int ct = 0; ct < 2; ++ct)
        b[ct] = *(const bf16x8*)&Bp[(size_t)(j * 512 + (wc * 2 + ct) * 64 + lane) * 8];
#pragma unroll
      for (int rt = 0; rt < 4; ++rt)
#pragma unroll
        for (int ct = 0; ct < 2; ++ct)
          acc[rt * 2 + ct] = __builtin_amdgcn_mfma_f32_16x16x32_bf16(a[rt], b[ct], acc[rt * 2 + ct], 0, 0, 0);
    }
  };

  // ---- prologue ----
  stageW(0);
  stageA(0, 0);
  BARX0();

  // ---- master loop: NU units, one barrier each ----
#pragma unroll
  for (int u = 0; u < NU; ++u) {
    if (u + 1 < NU) stageW(u + 1);
    if (u + 1 < NL1) stageA(u + 1, (u + 1) & 1);
    if (u < NL1)          compA2(u);
    else if (u < NL1 + 4) compH2(u);
    else                  compL3x4(u);
    if (u == NL1 - 1) {
      BARX0();        // all As reads done, stage W(u+1) drained
      writeH(b1v);    // H1 (overwrites As region too)
      BARLG();
    } else if (u == NL1 + 3) {
      BARX0();
      writeH(b2v);    // H2
      BARLG();
    } else if (u + 1 < NU) {
      BARX0();
    }
  }

  // ---- epilogue: bias + cross-wave LayerNorm + residual ----
  float b3v[2], gv[2], bev[2];
#pragma unroll
  for (int ct = 0; ct < 2; ++ct) {
    int col = wc * 32 + ct * 16 + l16;
    b3v[ct] = b3[col]; gv[ct] = gam[col]; bev[ct] = bet[col];
  }
#pragma unroll
  for (int rt = 0; rt < 4; ++rt)
#pragma unroll
    for (int q = 0; q < 4; ++q) {
      int row = wr * 64 + rt * 16 + kg * 4 + q;
      float x0 = acc[rt * 2 + 0][q] + b3v[0];
      float x1 = acc[rt * 2 + 1][q] + b3v[1];
      acc[rt * 2 + 0][q] = x0;
      acc[rt * 2 + 1][q] = x1;
      float s1 = x0 + x1, s2 = x0 * x0 + x1 * x1;
#pragma unroll
      for (int m = 1; m <= 8; m <<= 1) { s1 += __shfl_xor(s1, m); s2 += __shfl_xor(s2, m); }
      if (l16 == 0) pbuf[row * 4 + wc] = make_float2(s1, s2);
    }
  __syncthreads();
#pragma unroll
  for (int rt = 0; rt < 4; ++rt)
#pragma unroll
    for (int q = 0; q < 4; ++q) {
      int row = wr * 64 + rt * 16 + kg * 4 + q;
      float2 p0 = pbuf[row * 4 + 0];
      float2 p1 = pbuf[row * 4 + 1];
      float2 p2 = pbuf[row * 4 + 2];
      float2 p3 = pbuf[row * 4 + 3];
      float S1 = p0.x + p1.x + p2.x + p3.x;
      float S2 = p0.y + p1.y + p2.y + p3.y;
      float mu = S1 * (1.f / 128.f);
      float var = S2 * (1.f / 128.f) - mu * mu;
      float rs = rsqrtf(var + 1e-5f);
      int rg = m0 + row;
      if (rg < M) {
        const float* resid = (IS_EDGE ? edge_emb_f : node_emb_f) + (size_t)rg * 128;
        float* op = out_base + (size_t)rg * 128;
#pragma unroll
        for (int ct = 0; ct < 2; ++ct) {
          int col = wc * 32 + ct * 16 + l16;
          op[col] = (acc[rt * 2 + ct][q] - mu) * rs * gv[ct] + bev[ct] + resid[col];
        }
      }
    }
}

extern "C" void kernel_launch(void* const* d_in, const int* in_sizes, int n_in,
                              void* d_out, int out_size, void* d_ws, size_t ws_size,
                              hipStream_t stream) {
  const float* node_emb = (const float*)d_in[0];
  const float* edge_emb = (const float*)d_in[1];
  const int*   src      = (const int*)d_in[2];
  const int*   dst      = (const int*)d_in[3];
  const float* eW1 = (const float*)d_in[5];
  const float* eb1 = (const float*)d_in[6];
  const float* eW2 = (const float*)d_in[7];
  const float* eb2 = (const float*)d_in[8];
  const float* eW3 = (const float*)d_in[9];
  const float* eb3 = (const float*)d_in[10];
  const float* eg  = (const float*)d_in[11];
  const float* ebt = (const float*)d_in[12];
  const float* nW1 = (const float*)d_in[13];
  const float* nb1 = (const float*)d_in[14];
  const float* nW2 = (const float*)d_in[15];
  const float* nb2 = (const float*)d_in[16];
  const float* nW3 = (const float*)d_in[17];
  const float* nb3 = (const float*)d_in[18];
  const float* ng  = (const float*)d_in[19];
  const float* nbt = (const float*)d_in[20];

  const int Nn = in_sizes[0] / 128;
  const int Ee = in_sizes[2];

  char* ws = (char*)d_ws;
  short* aggb   = (short*)ws;  ws += (size_t)Nn * 128 * 2;
  short* nodebf = (short*)ws;  ws += (size_t)Nn * 128 * 2;
  int* cnt_i  = (int*)ws;      ws += (size_t)Nn * 4;
  int* cursor = (int*)ws;      ws += (size_t)Nn * 4;
  int* offv   = (int*)ws;      ws += (size_t)(Nn + 1) * 4;
  int* eidx   = (int*)ws;      ws += (size_t)Ee * 4;
  ws = (char*)(((uintptr_t)ws + 15) & ~(uintptr_t)15);
  short* eAll = (short*)ws;          // W1 12x8192 | W2 8x8192 | W3 8x4096 = 196608 shorts
  short* nAll = eAll + 196608;       // W1 8x8192 | W2 8x8192 | W3 8x4096 = 163840 shorts

  float* out_node = (float*)d_out;
  float* out_edge = out_node + (size_t)Nn * 128;

  hipMemsetAsync(cnt_i, 0, (size_t)Nn * 4, stream);

  cvt_kernel<<<2048, 256, 0, stream>>>(node_emb, nodebf, (long)Nn * 16);

  prep_kernel<false><<<48, 256, 0, stream>>>(eW1, eAll, 384, 256);
  prep_kernel<true><<<32, 256, 0, stream>>>(eW2, eAll + 98304, 256, 256);
  prep_kernel<true><<<16, 256, 0, stream>>>(eW3, eAll + 163840, 256, 128);
  prep_kernel<false><<<32, 256, 0, stream>>>(nW1, nAll, 256, 256);
  prep_kernel<true><<<32, 256, 0, stream>>>(nW2, nAll + 65536, 256, 256);
  prep_kernel<true><<<16, 256, 0, stream>>>(nW3, nAll + 131072, 256, 128);

  count_kernel<<<(Ee + 255) / 256, 256, 0, stream>>>(dst, cnt_i, Ee);
  scan_kernel<<<1, 1024, 0, stream>>>(cnt_i, offv, cursor, Nn);
  scatter_kernel<<<(Ee + 255) / 256, 256, 0, stream>>>(dst, cursor, eidx, Ee);

  mlp_kernel<true><<<(Ee + 127) / 128, 512, 135168, stream>>>(
      node_emb, edge_emb, nodebf, aggb, src, dst, eAll,
      eb1, eb2, eb3, eg, ebt, out_edge, Ee);

  agg_kernel<<<(Nn + 3) / 4, 256, 0, stream>>>(out_edge, eidx, offv, aggb, Nn);

  mlp_kernel<false><<<(Nn + 127) / 128, 512, 135168, stream>>>(
      node_emb, edge_emb, nodebf, aggb, src, dst, nAll,
      nb1, nb2, nb3, ng, nbt, out_node, Nn);
}

// Round 11
// 673.283 us; speedup vs baseline: 1.3652x; 1.2543x over previous
//
#include <hip/hip_runtime.h>
#include <hip/hip_bf16.h>

typedef __attribute__((ext_vector_type(8))) short bf16x8;
typedef __attribute__((ext_vector_type(4))) short s16x4;
typedef __attribute__((ext_vector_type(4))) float f32x4;

__device__ __forceinline__ short f2bf(float f) {
  union { __hip_bfloat16 h; short s; } u;
  u.h = __float2bfloat16(f);
  return u.s;
}

__device__ __forceinline__ void gld_lds16(const short* g, short* l) {
  __builtin_amdgcn_global_load_lds((const __attribute__((address_space(1))) unsigned*)g,
                                   (__attribute__((address_space(3))) unsigned*)l,
                                   16, 0, 0);
}

#define BARX(N) asm volatile("s_waitcnt vmcnt(" #N ") lgkmcnt(0)\ns_barrier" ::: "memory")
#define BARLG() asm volatile("s_waitcnt lgkmcnt(0)\ns_barrier" ::: "memory")

// fp32 -> bf16 bulk convert
__global__ void cvt_kernel(const float* __restrict__ in, short* __restrict__ out, long n8) {
  long i = (long)blockIdx.x * blockDim.x + threadIdx.x;
  const long stride = (long)gridDim.x * blockDim.x;
  for (; i < n8; i += stride) {
    const float* p = in + i * 8;
    float4 a = *(const float4*)p, b = *(const float4*)(p + 4);
    bf16x8 o;
    o[0] = f2bf(a.x); o[1] = f2bf(a.y); o[2] = f2bf(a.z); o[3] = f2bf(a.w);
    o[4] = f2bf(b.x); o[5] = f2bf(b.y); o[6] = f2bf(b.z); o[7] = f2bf(b.w);
    *(bf16x8*)(out + i * 8) = o;
  }
}

// W[K][N] fp32 -> bf16 fragment slots: slot s = (kc*(N/16)+f)*64 + lane, lane=(kg,l16)
// content: W[k(kc*32+kg*8+e)][f*16+l16].  PERM: k-col permutation matching H storage:
// k = (kh & ~63) | ((kh&3)<<4) | ((kh>>2)&15)
template <bool PERM>
__global__ void prep_kernel(const float* __restrict__ W, short* __restrict__ out, int K, int N) {
  int s = blockIdx.x * 256 + threadIdx.x;
  int NF = N >> 4;
  int total = (K >> 5) * NF * 64;
  if (s >= total) return;
  int l = s & 63, kcf = s >> 6;
  int kc = kcf / NF, f = kcf - kc * NF;
  int kg = l >> 4, l16 = l & 15;
  bf16x8 o;
#pragma unroll
  for (int e = 0; e < 8; ++e) {
    int kh = kc * 32 + kg * 8 + e;
    int k = PERM ? ((kh & ~63) | ((kh & 3) << 4) | ((kh >> 2) & 15)) : kh;
    o[e] = f2bf(W[(size_t)k * N + f * 16 + l16]);
  }
  *(bf16x8*)(out + (size_t)s * 8) = o;
}

// ---------------- CSR aggregation ----------------
__global__ void count_kernel(const int* __restrict__ dst, int* __restrict__ cnt, int E) {
  int i = blockIdx.x * 256 + threadIdx.x;
  if (i < E) atomicAdd(&cnt[dst[i]], 1);
}

// per-2048-node block sums
__global__ void bsum_kernel(const int* __restrict__ cnt, int* __restrict__ bsum, int N) {
  __shared__ int wsum[4];
  int b = blockIdx.x, t = threadIdx.x;
  int base = b * 2048;
  int s = 0;
#pragma unroll
  for (int j = 0; j < 8; ++j) {
    int i = base + j * 256 + t;
    s += (i < N) ? cnt[i] : 0;
  }
#pragma unroll
  for (int m = 1; m < 64; m <<= 1) s += __shfl_xor(s, m);
  if ((t & 63) == 0) wsum[t >> 6] = s;
  __syncthreads();
  if (t == 0) bsum[b] = wsum[0] + wsum[1] + wsum[2] + wsum[3];
}

// exclusive scan of block sums (nb <= 64)
__global__ void bscan_kernel(int* __restrict__ bsum, int nb) {
  int l = threadIdx.x;
  int v = (l < nb) ? bsum[l] : 0;
  int x = v;
#pragma unroll
  for (int d = 1; d < 64; d <<= 1) { int y = __shfl_up(x, d); if (l >= d) x += y; }
  if (l < nb) bsum[l] = x - v;
}

// per-node exclusive offsets using scanned block sums
__global__ void offs_kernel(const int* __restrict__ cnt, const int* __restrict__ bsum,
                            int* __restrict__ off, int* __restrict__ cursor, int N) {
  __shared__ int wpre[4];
  int b = blockIdx.x, t = threadIdx.x, w = t >> 6, l = t & 63;
  int base = b * 2048;
  int v[8];
  int s = 0;
#pragma unroll
  for (int j = 0; j < 8; ++j) {
    int i = base + t * 8 + j;
    v[j] = (i < N) ? cnt[i] : 0;
    s += v[j];
  }
  int x = s;
#pragma unroll
  for (int d = 1; d < 64; d <<= 1) { int y = __shfl_up(x, d); if (l >= d) x += y; }
  if (l == 63) wpre[w] = x;
  __syncthreads();
  int wo = 0;
  for (int k = 0; k < w; ++k) wo += wpre[k];
  int excl = bsum[b] + wo + x - s;
#pragma unroll
  for (int j = 0; j < 8; ++j) {
    int i = base + t * 8 + j;
    if (i < N) { off[i] = excl; cursor[i] = excl; }
    excl += v[j];
  }
  if (b == gridDim.x - 1 && t == 255) off[N] = excl;
}

__global__ void scatter_kernel(const int* __restrict__ dst, int* __restrict__ cursor,
                               int* __restrict__ eidx, int E) {
  int e = blockIdx.x * 256 + threadIdx.x;
  if (e < E) {
    int p = atomicAdd(&cursor[dst[e]], 1);
    eidx[p] = e;
  }
}

// per-node gather-mean of new edge embeddings -> bf16
__global__ void agg_kernel(const float* __restrict__ edge_out, const int* __restrict__ eidx,
                           const int* __restrict__ off, short* __restrict__ aggb, int N) {
  int n = blockIdx.x * 4 + (threadIdx.x >> 6);
  if (n >= N) return;
  int l = threadIdx.x & 63;
  int beg = off[n], end = off[n + 1];
  float ax = 0.f, ay = 0.f;
  int i = beg;
  for (; i + 4 <= end; i += 4) {
    int e0 = eidx[i], e1 = eidx[i + 1], e2 = eidx[i + 2], e3 = eidx[i + 3];
    float2 v0 = *(const float2*)(edge_out + (size_t)e0 * 128 + l * 2);
    float2 v1 = *(const float2*)(edge_out + (size_t)e1 * 128 + l * 2);
    float2 v2 = *(const float2*)(edge_out + (size_t)e2 * 128 + l * 2);
    float2 v3 = *(const float2*)(edge_out + (size_t)e3 * 128 + l * 2);
    ax += v0.x + v1.x + v2.x + v3.x;
    ay += v0.y + v1.y + v2.y + v3.y;
  }
  for (; i < end; ++i) {
    int e = eidx[i];
    float2 v = *(const float2*)(edge_out + (size_t)e * 128 + l * 2);
    ax += v.x; ay += v.y;
  }
  float inv = 1.0f / fmaxf((float)(end - beg), 1.0f);
  unsigned pk = ((unsigned)(unsigned short)f2bf(ay * inv) << 16) |
                (unsigned)(unsigned short)f2bf(ax * inv);
  *(unsigned*)&aggb[(size_t)n * 128 + l * 2] = pk;
}

struct F8 { float4 a, b; };

// ---------------- fused 3-layer MLP + LN, BM=128, 512 thr, 112 KB LDS ----------------
// 16 KB weight units (K=32), TRIPLE-buffered, staged depth-2 with counted vmcnt (R5 schedule).
// L1/L2: waves 2(row wr)x4(col wc), each 64r x 64c (4x4 frags).
// L3: row-split, wave w owns rows w*16..+15, all 128 cols; per-wave LN.
// A chunks (8 KB, K=32) triple-buffered, overlaid on Hs (dead until H1).
// H: addr(row, ch) = row*256 + (ch ^ ((row&7)<<3)); position ch holds col
// c = ((ch&3)<<4)|((ch>>2)&15) per 64-block (matches PERM'd W2/W3 K-order).
template <bool IS_EDGE>
__launch_bounds__(512)
__global__ void mlp_kernel(const float* __restrict__ node_emb_f, const float* __restrict__ edge_emb_f,
                           const short* __restrict__ node_bf, const short* __restrict__ agg_bf,
                           const int* __restrict__ src, const int* __restrict__ dst,
                           const short* __restrict__ wAll,
                           const float* __restrict__ b1, const float* __restrict__ b2,
                           const float* __restrict__ b3,
                           const float* __restrict__ gam, const float* __restrict__ bet,
                           float* __restrict__ out_base, int M) {
  extern __shared__ short smem[];
  short* Bs = smem;            // 3 x 8192 shorts (48 KB) weight triple-buffer
  short* Hs = smem + 24576;    // 32768 shorts (64 KB); As triple overlay = first 12288 shorts

  const int tid = threadIdx.x;
  const int m0 = blockIdx.x * 128;
  const int w = tid >> 6, lane = tid & 63, l16 = lane & 15, kg = lane >> 4;
  const int wr = w >> 2, wc = w & 3;

  constexpr int NL1 = IS_EDGE ? 12 : 8;

  // A staging identity: slot tid <-> row grow, k-byte-group gcq
  const int grow = ((tid >> 6) & 7) * 16 + (tid & 15);
  const int gcq = ((tid >> 4) & 3) * 8;
  const int grc = min(m0 + grow, M - 1);
  int gsr = 0, gdr = 0;
  if (IS_EDGE) { gsr = src[grc]; gdr = dst[grc]; }

  float b1v[4], b2v[4];
#pragma unroll
  for (int ct = 0; ct < 4; ++ct) {
    int col = wc * 64 + ct * 16 + l16;
    b1v[ct] = b1[col];
    b2v[ct] = b2[col];
  }
  float b3v[8], gv[8], bev[8];
#pragma unroll
  for (int f = 0; f < 8; ++f) {
    int col = f * 16 + l16;
    b3v[f] = b3[col]; gv[f] = gam[col]; bev[f] = bet[col];
  }

  f32x4 acc[16];
#pragma unroll
  for (int i = 0; i < 16; ++i) { f32x4 z = {0.f, 0.f, 0.f, 0.f}; acc[i] = z; }

  auto stageW = [&](int v) {   // 2 vm ops/thread
    const short* g = wAll + (size_t)v * 8192;
    short* l = Bs + (size_t)(v % 3) * 8192;
    gld_lds16(g + (size_t)tid * 8, l + (size_t)tid * 8);
    gld_lds16(g + (size_t)(tid + 512) * 8, l + (size_t)(tid + 512) * 8);
  };
  auto stageAb = [&](int v) {  // bf16 source path: 1 vm op/thread, direct to LDS
    short* dstp = Hs + (size_t)(v % 3) * 4096 + (size_t)tid * 8;
    int col = v * 32 + gcq;
    const short* q;
    if (IS_EDGE) {
      q = node_bf + (size_t)(col < 128 ? gsr : gdr) * 128 + (col & 127);
    } else {
      q = (col < 128) ? node_bf + (size_t)grc * 128 + col
                      : agg_bf + (size_t)grc * 128 + (col - 128);
    }
    gld_lds16(q, dstp);
  };
  auto loadAf = [&](int v) -> F8 {  // fp32 edge region: issue loads (2 vm)
    const float* q = edge_emb_f + (size_t)grc * 128 + (v * 32 + gcq - 256);
    F8 r;
    r.a = *(const float4*)q;
    r.b = *(const float4*)(q + 4);
    return r;
  };
  auto storeAf = [&](int v, const F8& p) {  // consume + ds_write
    float t[8];
    *(float4*)t = p.a; *(float4*)(t + 4) = p.b;
    bf16x8 o;
#pragma unroll
    for (int e = 0; e < 8; ++e) o[e] = f2bf(t[e]);
    *(bf16x8*)(Hs + (size_t)(v % 3) * 4096 + (size_t)tid * 8) = o;
  };

  auto compA = [&](int u) {
    const short* Ap = Hs + (size_t)(u % 3) * 4096;
    const short* Bp = Bs + (size_t)(u % 3) * 8192;
    bf16x8 a[4], b[4];
#pragma unroll
    for (int rt = 0; rt < 4; ++rt)
      a[rt] = *(const bf16x8*)&Ap[(size_t)((wr * 4 + rt) * 64 + lane) * 8];
#pragma unroll
    for (int ct = 0; ct < 4; ++ct)
      b[ct] = *(const bf16x8*)&Bp[(size_t)((wc * 4 + ct) * 64 + lane) * 8];
#pragma unroll
    for (int rt = 0; rt < 4; ++rt)
#pragma unroll
      for (int ct = 0; ct < 4; ++ct)
        acc[rt * 4 + ct] = __builtin_amdgcn_mfma_f32_16x16x32_bf16(a[rt], b[ct], acc[rt * 4 + ct], 0, 0, 0);
  };

  auto compH = [&](int kc, const short* Bp) {
    bf16x8 a[4], b[4];
#pragma unroll
    for (int rt = 0; rt < 4; ++rt) {
      int row = wr * 64 + rt * 16 + l16;
      int ch = (kc * 32 + kg * 8) ^ ((row & 7) << 3);
      a[rt] = *(const bf16x8*)&Hs[(size_t)row * 256 + ch];
    }
#pragma unroll
    for (int ct = 0; ct < 4; ++ct)
      b[ct] = *(const bf16x8*)&Bp[(size_t)((wc * 4 + ct) * 64 + lane) * 8];
#pragma unroll
    for (int rt = 0; rt < 4; ++rt)
#pragma unroll
      for (int ct = 0; ct < 4; ++ct)
        acc[rt * 4 + ct] = __builtin_amdgcn_mfma_f32_16x16x32_bf16(a[rt], b[ct], acc[rt * 4 + ct], 0, 0, 0);
  };

  auto writeH = [&](const float* bv) {
#pragma unroll
    for (int rt = 0; rt < 4; ++rt)
#pragma unroll
      for (int q = 0; q < 4; ++q) {
        int row = wr * 64 + rt * 16 + kg * 4 + q;
        s16x4 v;
#pragma unroll
        for (int ct = 0; ct < 4; ++ct)
          v[ct] = f2bf(fmaxf(acc[rt * 4 + ct][q] + bv[ct], 0.f));
        int ch = (wc * 64 + l16 * 4) ^ ((row & 7) << 3);
        *(s16x4*)&Hs[(size_t)row * 256 + ch] = v;
      }
#pragma unroll
    for (int i = 0; i < 16; ++i) { f32x4 z = {0.f, 0.f, 0.f, 0.f}; acc[i] = z; }
  };

  auto compL3 = [&](int kk, const short* Bp) {  // row-split: wave w rows w*16..+15, 128 cols
    int row = w * 16 + l16;
    int ch = (kk * 32 + kg * 8) ^ ((row & 7) << 3);
    bf16x8 a = *(const bf16x8*)&Hs[(size_t)row * 256 + ch];
    const short* Bsub = Bp + (size_t)(kk & 1) * 4096;
#pragma unroll
    for (int f = 0; f < 8; ++f) {
      bf16x8 b = *(const bf16x8*)&Bsub[(size_t)(f * 64 + lane) * 8];
      acc[f] = __builtin_amdgcn_mfma_f32_16x16x32_bf16(a, b, acc[f], 0, 0, 0);
    }
  };

  // ---- prologue: issue order W0,A0,W1,A1 so BARX(3) drains {W0,A0}, leaves {W1,A1} ----
  stageW(0);
  stageAb(0);
  stageW(1);
  stageAb(1);
  BARX(3);

  // ---- L1 sub-loop A: u in [0,6) — stages A(2..7), all bf16 (1 vm) ----
#pragma unroll 1
  for (int u = 0; u < 6; ++u) {
    stageW(u + 2);
    stageAb(u + 2);
    compA(u);
    BARX(3);
  }

  if (IS_EDGE) {
    // ---- L1 sub-loop B: u in [6,10) — stages A(8..11), fp32 load-early/store-late ----
#pragma unroll 1
    for (int u = 6; u < 10; ++u) {
      F8 p = loadAf(u + 2);   // issue loads FIRST (FIFO: consume drains older, leaves W)
      stageW(u + 2);
      compA(u);
      storeAf(u + 2, p);      // consume (implicit wait drains through these loads)
      BARX(2);
    }
  }

  // ---- L1 sub-loop C: u in [NL1-2, NL1) — no A staging ----
#pragma unroll 1
  for (int u = NL1 - 2; u < NL1; ++u) {
    stageW(u + 2);
    compA(u);
    BARX(2);
  }
  writeH(b1v);
  BARLG();

  // ---- layer 2: u in [NL1, NL1+8) ----
#pragma unroll 1
  for (int u = NL1; u < NL1 + 8; ++u) {
    stageW(u + 2);
    compH(u - NL1, Bs + (size_t)(u % 3) * 8192);
    BARX(2);
  }
  writeH(b2v);
  BARLG();

  // ---- layer 3: 4 units x 2 chunks ----
  {
    const int us = NL1 + 8;
#pragma unroll 1
    for (int k = 0; k < 2; ++k) {
      int u = us + k;
      stageW(u + 2);
      const short* Bp = Bs + (size_t)(u % 3) * 8192;
      compL3(2 * k, Bp);
      compL3(2 * k + 1, Bp);
      BARX(2);
    }
    {
      const short* Bp = Bs + (size_t)((us + 2) % 3) * 8192;
      compL3(4, Bp);
      compL3(5, Bp);
      BARX(0);
    }
    {
      const short* Bp = Bs + (size_t)((us + 3) % 3) * 8192;
      compL3(6, Bp);
      compL3(7, Bp);
    }
  }

  // ---- epilogue: bias + per-wave LayerNorm + residual ----
#pragma unroll
  for (int q = 0; q < 4; ++q) {
    int rg = m0 + w * 16 + kg * 4 + q;
    float o[8], s1 = 0.f, s2 = 0.f;
#pragma unroll
    for (int f = 0; f < 8; ++f) {
      float x = acc[f][q] + b3v[f];
      o[f] = x; s1 += x; s2 += x * x;
    }
#pragma unroll
    for (int m = 1; m <= 8; m <<= 1) { s1 += __shfl_xor(s1, m); s2 += __shfl_xor(s2, m); }
    float mu = s1 * (1.f / 128.f);
    float var = s2 * (1.f / 128.f) - mu * mu;
    float rs = rsqrtf(var + 1e-5f);
    if (rg < M) {
      const float* resid = (IS_EDGE ? edge_emb_f : node_emb_f) + (size_t)rg * 128;
      float* op = out_base + (size_t)rg * 128;
#pragma unroll
      for (int f = 0; f < 8; ++f) {
        int col = f * 16 + l16;
        op[col] = (o[f] - mu) * rs * gv[f] + bev[f] + resid[col];
      }
    }
  }
}

extern "C" void kernel_launch(void* const* d_in, const int* in_sizes, int n_in,
                              void* d_out, int out_size, void* d_ws, size_t ws_size,
                              hipStream_t stream) {
  const float* node_emb = (const float*)d_in[0];
  const float* edge_emb = (const float*)d_in[1];
  const int*   src      = (const int*)d_in[2];
  const int*   dst      = (const int*)d_in[3];
  const float* eW1 = (const float*)d_in[5];
  const float* eb1 = (const float*)d_in[6];
  const float* eW2 = (const float*)d_in[7];
  const float* eb2 = (const float*)d_in[8];
  const float* eW3 = (const float*)d_in[9];
  const float* eb3 = (const float*)d_in[10];
  const float* eg  = (const float*)d_in[11];
  const float* ebt = (const float*)d_in[12];
  const float* nW1 = (const float*)d_in[13];
  const float* nb1 = (const float*)d_in[14];
  const float* nW2 = (const float*)d_in[15];
  const float* nb2 = (const float*)d_in[16];
  const float* nW3 = (const float*)d_in[17];
  const float* nb3 = (const float*)d_in[18];
  const float* ng  = (const float*)d_in[19];
  const float* nbt = (const float*)d_in[20];

  const int Nn = in_sizes[0] / 128;
  const int Ee = in_sizes[2];
  const int nb2048 = (Nn + 2047) / 2048;   // <= 64 required by bscan_kernel

  char* ws = (char*)d_ws;
  short* aggb   = (short*)ws;  ws += (size_t)Nn * 128 * 2;
  short* nodebf = (short*)ws;  ws += (size_t)Nn * 128 * 2;
  int* cnt_i  = (int*)ws;      ws += (size_t)Nn * 4;
  int* cursor = (int*)ws;      ws += (size_t)Nn * 4;
  int* offv   = (int*)ws;      ws += (size_t)(Nn + 1) * 4;
  int* eidx   = (int*)ws;      ws += (size_t)Ee * 4;
  int* bsum   = (int*)ws;      ws += 64 * 4;
  ws = (char*)(((uintptr_t)ws + 15) & ~(uintptr_t)15);
  short* eAll = (short*)ws;          // W1 12x8192 | W2 8x8192 | W3 8x4096 = 196608 shorts
  short* nAll = eAll + 196608;       // W1 8x8192 | W2 8x8192 | W3 8x4096 = 163840 shorts

  float* out_node = (float*)d_out;
  float* out_edge = out_node + (size_t)Nn * 128;

  hipMemsetAsync(cnt_i, 0, (size_t)Nn * 4, stream);

  cvt_kernel<<<2048, 256, 0, stream>>>(node_emb, nodebf, (long)Nn * 16);

  prep_kernel<false><<<48, 256, 0, stream>>>(eW1, eAll, 384, 256);
  prep_kernel<true><<<32, 256, 0, stream>>>(eW2, eAll + 98304, 256, 256);
  prep_kernel<true><<<16, 256, 0, stream>>>(eW3, eAll + 163840, 256, 128);
  prep_kernel<false><<<32, 256, 0, stream>>>(nW1, nAll, 256, 256);
  prep_kernel<true><<<32, 256, 0, stream>>>(nW2, nAll + 65536, 256, 256);
  prep_kernel<true><<<16, 256, 0, stream>>>(nW3, nAll + 131072, 256, 128);

  count_kernel<<<(Ee + 255) / 256, 256, 0, stream>>>(dst, cnt_i, Ee);
  bsum_kernel<<<nb2048, 256, 0, stream>>>(cnt_i, bsum, Nn);
  bscan_kernel<<<1, 64, 0, stream>>>(bsum, nb2048);
  offs_kernel<<<nb2048, 256, 0, stream>>>(cnt_i, bsum, offv, cursor, Nn);
  scatter_kernel<<<(Ee + 255) / 256, 256, 0, stream>>>(dst, cursor, eidx, Ee);

  mlp_kernel<true><<<(Ee + 127) / 128, 512, 114688, stream>>>(
      node_emb, edge_emb, nodebf, aggb, src, dst, eAll,
      eb1, eb2, eb3, eg, ebt, out_edge, Ee);

  agg_kernel<<<(Nn + 3) / 4, 256, 0, stream>>>(out_edge, eidx, offv, aggb, Nn);

  mlp_kernel<false><<<(Nn + 127) / 128, 512, 114688, stream>>>(
      node_emb, edge_emb, nodebf, aggb, src, dst, nAll,
      nb1, nb2, nb3, ng, nbt, out_node, Nn);
}